// Round 1
// baseline (1509.251 us; speedup 1.0000x reference)
//
#include <hip/hip_runtime.h>
#include <hip/hip_fp16.h>

#define B_  2
#define S_  2048
#define NH  16
#define HD  64
#define DM  1024
#define SCAL 0.125f

typedef _Float16 f16;
typedef _Float16 f16x4 __attribute__((ext_vector_type(4)));
typedef _Float16 f16x8 __attribute__((ext_vector_type(8)));
typedef float    f32x4 __attribute__((ext_vector_type(4)));

#define MFMA16(a,b,c) __builtin_amdgcn_mfma_f32_16x16x32_f16(a,b,c,0,0,0)

// ---------------------------------------------------------------------------
// GEMM: C[M=4096][N=1024] = X @ W^T + bias   (W row-major [out][in])
// MODE 0: q  -> perm fp16 [b][n][seq][64], scaled by SCAL
// MODE 1: k  -> perm fp16 [b][n][seq][64]
// MODE 2: v  -> transposed fp16 [b][n][64][seq]
// MODE 3: out-proj: X = 4 fp32 partials (summed), out fp32 [m][n]
// ---------------------------------------------------------------------------
template<int MODE>
__global__ __launch_bounds__(256) void gemm_k(const float* __restrict__ X,
    const float* __restrict__ W, const float* __restrict__ bias,
    void* __restrict__ outp, float scale)
{
    __shared__ __align__(16) f16 As[128][40];   // pad 32->40 halves (80B stride)
    __shared__ __align__(16) f16 Bs[128][40];
    const int tid = threadIdx.x;
    const int wave = tid >> 6, lane = tid & 63;
    const int wm = wave >> 1, wn = wave & 1;
    const int lr = lane & 15, lg = lane >> 4;
    const int m0 = blockIdx.x * 128, n0 = blockIdx.y * 128;

    f32x4 acc[4][4];
    #pragma unroll
    for (int s = 0; s < 4; s++)
        #pragma unroll
        for (int f = 0; f < 4; f++) acc[s][f] = (f32x4)(0.0f);

    const int srow = tid >> 3;          // 0..31
    const int sk4  = (tid & 7) * 4;     // 0..28

    for (int kt = 0; kt < DM; kt += 32) {
        __syncthreads();
        #pragma unroll
        for (int i = 0; i < 4; i++) {
            const int r = srow + i * 32;
            float4 va;
            const float* xp = X + (size_t)(m0 + r) * DM + kt + sk4;
            if (MODE == 3) {
                float4 p0 = *(const float4*)xp;
                float4 p1 = *(const float4*)(xp + 4194304);
                float4 p2 = *(const float4*)(xp + 8388608);
                float4 p3 = *(const float4*)(xp + 12582912);
                va.x = p0.x + p1.x + p2.x + p3.x;
                va.y = p0.y + p1.y + p2.y + p3.y;
                va.z = p0.z + p1.z + p2.z + p3.z;
                va.w = p0.w + p1.w + p2.w + p3.w;
            } else {
                va = *(const float4*)xp;
            }
            f16x4 ha = { (f16)va.x, (f16)va.y, (f16)va.z, (f16)va.w };
            *(f16x4*)&As[r][sk4] = ha;
            float4 vb = *(const float4*)(W + (size_t)(n0 + r) * DM + kt + sk4);
            f16x4 hb = { (f16)vb.x, (f16)vb.y, (f16)vb.z, (f16)vb.w };
            *(f16x4*)&Bs[r][sk4] = hb;
        }
        __syncthreads();
        f16x8 af[4], bf[4];
        #pragma unroll
        for (int s = 0; s < 4; s++) af[s] = *(const f16x8*)&As[wm*64 + s*16 + lr][lg*8];
        #pragma unroll
        for (int f = 0; f < 4; f++) bf[f] = *(const f16x8*)&Bs[wn*64 + f*16 + lr][lg*8];
        #pragma unroll
        for (int s = 0; s < 4; s++)
            #pragma unroll
            for (int f = 0; f < 4; f++)
                acc[s][f] = MFMA16(af[s], bf[f], acc[s][f]);
    }

    float bcol[4];
    #pragma unroll
    for (int f = 0; f < 4; f++) bcol[f] = bias[n0 + wn*64 + f*16 + lr];

    #pragma unroll
    for (int s = 0; s < 4; s++) {
        const int mg = m0 + wm*64 + s*16 + lg*4;   // + r
        #pragma unroll
        for (int f = 0; f < 4; f++) {
            const int nc = n0 + wn*64 + f*16 + lr;
            if (MODE == 3) {
                float* o = (float*)outp;
                #pragma unroll
                for (int r = 0; r < 4; r++)
                    o[(size_t)(mg + r) * DM + nc] = acc[s][f][r] + bcol[f];
            } else {
                const int b = mg >> 11, seq = mg & 2047;
                const int head = nc >> 6, h = nc & 63;
                f16* o = (f16*)outp;
                if (MODE == 2) {
                    f16x4 pk = { (f16)(acc[s][f][0] + bcol[f]), (f16)(acc[s][f][1] + bcol[f]),
                                 (f16)(acc[s][f][2] + bcol[f]), (f16)(acc[s][f][3] + bcol[f]) };
                    *(f16x4*)&o[((size_t)((b*NH + head)*HD + h)) * S_ + seq] = pk;
                } else {
                    #pragma unroll
                    for (int r = 0; r < 4; r++)
                        o[((size_t)(b*NH + head) * S_ + seq + r) * HD + h] =
                            (f16)((acc[s][f][r] + bcol[f]) * scale);
                }
            }
        }
    }
}

// ---------------------------------------------------------------------------
// Softmax denominators: l[b][q][n] = sum_k (masked ? 0 : exp(S))
// grid (qt=128, kchunk=4, b=2), 256 thr; wave -> 4 heads; k-split via atomicAdd
// ---------------------------------------------------------------------------
__global__ __launch_bounds__(256) void sums_k(const f16* __restrict__ qw,
    const f16* __restrict__ kw, const int* __restrict__ amask, float* __restrict__ l)
{
    const int tid = threadIdx.x, wave = tid >> 6, lane = tid & 63;
    const int lr = lane & 15, lg = lane >> 4;
    const int qt = blockIdx.x, kc = blockIdx.y, b = blockIdx.z;
    const int q0 = qt * 16, k0b = kc * 512;

    float rs[4][4];
    #pragma unroll
    for (int i = 0; i < 4; i++)
        #pragma unroll
        for (int r = 0; r < 4; r++) rs[i][r] = 0.f;

    f16x8 qf[4][2];
    #pragma unroll
    for (int hh = 0; hh < 4; hh++) {
        const int n = wave * 4 + hh;
        const f16* qp = qw + ((size_t)((b*NH + n) * S_) + q0 + lr) * HD + lg * 8;
        qf[hh][0] = *(const f16x8*)qp;
        qf[hh][1] = *(const f16x8*)(qp + 32);
    }
    for (int kt = 0; kt < 8; kt++) {
        const int k0 = k0b + kt * 64;
        int km[4];
        #pragma unroll
        for (int ct = 0; ct < 4; ct++) km[ct] = amask[b * S_ + k0 + ct*16 + lr];
        #pragma unroll
        for (int hh = 0; hh < 4; hh++) {
            const int n = wave * 4 + hh;
            const f16* kp = kw + ((size_t)((b*NH + n) * S_) + k0) * HD;
            #pragma unroll
            for (int ct = 0; ct < 4; ct++) {
                f16x8 b0 = *(const f16x8*)(kp + (size_t)(ct*16 + lr) * HD + lg*8);
                f16x8 b1 = *(const f16x8*)(kp + (size_t)(ct*16 + lr) * HD + 32 + lg*8);
                f32x4 sv = (f32x4)(0.f);
                sv = MFMA16(qf[hh][0], b0, sv);
                sv = MFMA16(qf[hh][1], b1, sv);
                #pragma unroll
                for (int r = 0; r < 4; r++) rs[hh][r] += km[ct] ? 0.f : __expf(sv[r]);
            }
        }
    }
    #pragma unroll
    for (int hh = 0; hh < 4; hh++) {
        #pragma unroll
        for (int r = 0; r < 4; r++) {
            float v = rs[hh][r];
            v += __shfl_xor(v, 1);  v += __shfl_xor(v, 2);
            v += __shfl_xor(v, 4);  v += __shfl_xor(v, 8);
            if (lr == 0)
                atomicAdd(&l[(size_t)(b*S_ + q0 + lg*4 + r) * NH + wave*4 + hh], v);
        }
    }
}

// ---------------------------------------------------------------------------
// Attention: recompute S, P = exp(S)/l (mask->0), write P to d_out (fp32),
// accumulate O_partial = P @ v per k-quarter.  No barriers (per-wave LDS).
// grid (qt=64, kq=4, b=2), 512 thr; wave -> (qhalf, 4 heads)
// ---------------------------------------------------------------------------
__global__ __launch_bounds__(512) void attn_k(const f16* __restrict__ qw,
    const f16* __restrict__ kw, const f16* __restrict__ vt,
    const int* __restrict__ amask, const float* __restrict__ l,
    float* __restrict__ attn, float* __restrict__ op)
{
    __shared__ __align__(16) f16 P2[8][16 * 72];   // per-wave P tile, k padded 64->72
    const int tid = threadIdx.x, wave = tid >> 6, lane = tid & 63;
    const int lr = lane & 15, lg = lane >> 4;
    const int qhalf = wave >> 2, hq = wave & 3;
    const int qt = blockIdx.x, kq = blockIdx.y, b = blockIdx.z;
    const int q0 = qt * 32 + qhalf * 16;
    const int k0b = kq * 512;
    f16* myP2 = P2[wave];

    f16x8 qf[4][2];
    float rl[4][4];
    #pragma unroll
    for (int hh = 0; hh < 4; hh++) {
        const int n = hq * 4 + hh;
        const f16* qp = qw + ((size_t)((b*NH + n) * S_) + q0 + lr) * HD + lg * 8;
        qf[hh][0] = *(const f16x8*)qp;
        qf[hh][1] = *(const f16x8*)(qp + 32);
        #pragma unroll
        for (int r = 0; r < 4; r++)
            rl[hh][r] = 1.0f / l[(size_t)(b*S_ + q0 + lg*4 + r) * NH + n];
    }
    f32x4 accO[4][4];
    #pragma unroll
    for (int i = 0; i < 4; i++)
        #pragma unroll
        for (int j = 0; j < 4; j++) accO[i][j] = (f32x4)(0.f);

    for (int kt = 0; kt < 8; kt++) {
        const int k0 = k0b + kt * 64;
        int km[4];
        #pragma unroll
        for (int ct = 0; ct < 4; ct++) km[ct] = amask[b * S_ + k0 + ct*16 + lr];
        #pragma unroll
        for (int hh = 0; hh < 4; hh++) {
            const int n = hq * 4 + hh;
            const f16* kp = kw + ((size_t)((b*NH + n) * S_) + k0) * HD;
            f32x4 sfr[4];
            #pragma unroll
            for (int ct = 0; ct < 4; ct++) {
                f16x8 b0 = *(const f16x8*)(kp + (size_t)(ct*16 + lr) * HD + lg*8);
                f16x8 b1 = *(const f16x8*)(kp + (size_t)(ct*16 + lr) * HD + 32 + lg*8);
                f32x4 sv = (f32x4)(0.f);
                sv = MFMA16(qf[hh][0], b0, sv);
                sv = MFMA16(qf[hh][1], b1, sv);
                sfr[ct] = sv;
            }
            #pragma unroll
            for (int ct = 0; ct < 4; ct++) {
                #pragma unroll
                for (int r = 0; r < 4; r++) {
                    float p = km[ct] ? 0.0f : __expf(sfr[ct][r]) * rl[hh][r];
                    attn[((size_t)(b*S_ + q0 + lg*4 + r) * S_ + (k0 + ct*16 + lr)) * NH + n] = p;
                    myP2[(lg*4 + r) * 72 + ct*16 + lr] = (f16)p;
                }
            }
            f16x8 a0 = *(const f16x8*)&myP2[lr * 72 + lg*8];
            f16x8 a1 = *(const f16x8*)&myP2[lr * 72 + 32 + lg*8];
            #pragma unroll
            for (int hb = 0; hb < 4; hb++) {
                const f16* vp = vt + ((size_t)((b*NH + n) * HD) + hb*16 + lr) * S_ + k0;
                f16x8 v0 = *(const f16x8*)(vp + lg*8);
                f16x8 v1 = *(const f16x8*)(vp + 32 + lg*8);
                accO[hh][hb] = MFMA16(a0, v0, accO[hh][hb]);
                accO[hh][hb] = MFMA16(a1, v1, accO[hh][hb]);
            }
        }
    }
    float* opk = op + (size_t)kq * 4194304;
    #pragma unroll
    for (int hh = 0; hh < 4; hh++) {
        const int n = hq * 4 + hh;
        #pragma unroll
        for (int hb = 0; hb < 4; hb++)
            #pragma unroll
            for (int r = 0; r < 4; r++)
                opk[(size_t)(b*S_ + q0 + lg*4 + r) * DM + n*HD + hb*16 + lr] = accO[hh][hb][r];
    }
}

// ---------------------------------------------------------------------------
extern "C" void kernel_launch(void* const* d_in, const int* in_sizes, int n_in,
                              void* d_out, int out_size, void* d_ws, size_t ws_size,
                              hipStream_t stream)
{
    const float* query = (const float*)d_in[0];
    const float* key   = (const float*)d_in[1];
    const float* value = (const float*)d_in[2];
    const int*   amask = (const int*)d_in[3];
    const float* Wq = (const float*)d_in[4];
    const float* bq = (const float*)d_in[5];
    const float* Wk = (const float*)d_in[6];
    const float* bk = (const float*)d_in[7];
    const float* Wv = (const float*)d_in[8];
    const float* bv = (const float*)d_in[9];
    const float* Wo = (const float*)d_in[10];
    const float* bo = (const float*)d_in[11];

    char* ws = (char*)d_ws;
    f16*   qw = (f16*)(ws + 0);            //  8 MB
    f16*   kw = (f16*)(ws + 8388608);      //  8 MB
    f16*   vt = (f16*)(ws + 16777216);     //  8 MB
    float* l  = (float*)(ws + 25165824);   // 256 KB
    float* op = (float*)(ws + 25427968);   // 64 MB (4 k-quarter partials)

    float* out0 = (float*)d_out;
    float* attn = out0 + 4194304;

    hipMemsetAsync(l, 0, 262144, stream);

    dim3 blk(256);
    dim3 g1(32, 8);
    gemm_k<0><<<g1, blk, 0, stream>>>(query, Wq, bq, (void*)qw, SCAL);
    gemm_k<1><<<g1, blk, 0, stream>>>(key,   Wk, bk, (void*)kw, 1.0f);
    gemm_k<2><<<g1, blk, 0, stream>>>(value, Wv, bv, (void*)vt, 1.0f);
    sums_k<<<dim3(128, 4, 2), blk, 0, stream>>>(qw, kw, amask, l);
    attn_k<<<dim3(64, 4, 2), dim3(512), 0, stream>>>(qw, kw, vt, amask, l, attn, op);
    gemm_k<3><<<g1, blk, 0, stream>>>(op, Wo, bo, d_out, 1.0f);
}

// Round 2
// 1180.166 us; speedup vs baseline: 1.2788x; 1.2788x over previous
//
#include <hip/hip_runtime.h>
#include <hip/hip_fp16.h>

#define B_  2
#define S_  2048
#define NH  16
#define HD  64
#define DM  1024
#define SCAL 0.125f
#define BSN (B_*S_*NH)   // 65536, stride of one lpart slab

typedef _Float16 f16;
typedef _Float16 f16x4 __attribute__((ext_vector_type(4)));
typedef _Float16 f16x8 __attribute__((ext_vector_type(8)));
typedef float    f32x4 __attribute__((ext_vector_type(4)));

#define MFMA16(a,b,c) __builtin_amdgcn_mfma_f32_16x16x32_f16(a,b,c,0,0,0)

// ---------------------------------------------------------------------------
// GEMM: C[M=4096][N=1024] = X @ W^T + bias   (W row-major [out][in])
// MODE 0: q  -> perm fp16 [b][n][seq][64], scaled by SCAL
// MODE 1: k  -> perm fp16 [b][n][seq][64]
// MODE 2: v  -> transposed fp16 [b][n][64][seq]
// MODE 3: out-proj: X = 2 fp32 partials (summed), out fp32 [m][n]
// ---------------------------------------------------------------------------
template<int MODE>
__global__ __launch_bounds__(256) void gemm_k(const float* __restrict__ X,
    const float* __restrict__ W, const float* __restrict__ bias,
    void* __restrict__ outp, float scale)
{
    __shared__ __align__(16) f16 As[128][40];   // pad 32->40 halves (80B stride)
    __shared__ __align__(16) f16 Bs[128][40];
    const int tid = threadIdx.x;
    const int wave = tid >> 6, lane = tid & 63;
    const int wm = wave >> 1, wn = wave & 1;
    const int lr = lane & 15, lg = lane >> 4;
    const int m0 = blockIdx.x * 128, n0 = blockIdx.y * 128;

    f32x4 acc[4][4];
    #pragma unroll
    for (int s = 0; s < 4; s++)
        #pragma unroll
        for (int f = 0; f < 4; f++) acc[s][f] = (f32x4)(0.0f);

    const int srow = tid >> 3;          // 0..31
    const int sk4  = (tid & 7) * 4;     // 0..28

    for (int kt = 0; kt < DM; kt += 32) {
        __syncthreads();
        #pragma unroll
        for (int i = 0; i < 4; i++) {
            const int r = srow + i * 32;
            float4 va;
            const float* xp = X + (size_t)(m0 + r) * DM + kt + sk4;
            if (MODE == 3) {
                float4 p0 = *(const float4*)xp;
                float4 p1 = *(const float4*)(xp + 4194304);
                va.x = p0.x + p1.x;
                va.y = p0.y + p1.y;
                va.z = p0.z + p1.z;
                va.w = p0.w + p1.w;
            } else {
                va = *(const float4*)xp;
            }
            f16x4 ha = { (f16)va.x, (f16)va.y, (f16)va.z, (f16)va.w };
            *(f16x4*)&As[r][sk4] = ha;
            float4 vb = *(const float4*)(W + (size_t)(n0 + r) * DM + kt + sk4);
            f16x4 hb = { (f16)vb.x, (f16)vb.y, (f16)vb.z, (f16)vb.w };
            *(f16x4*)&Bs[r][sk4] = hb;
        }
        __syncthreads();
        f16x8 af[4], bf[4];
        #pragma unroll
        for (int s = 0; s < 4; s++) af[s] = *(const f16x8*)&As[wm*64 + s*16 + lr][lg*8];
        #pragma unroll
        for (int f = 0; f < 4; f++) bf[f] = *(const f16x8*)&Bs[wn*64 + f*16 + lr][lg*8];
        #pragma unroll
        for (int s = 0; s < 4; s++)
            #pragma unroll
            for (int f = 0; f < 4; f++)
                acc[s][f] = MFMA16(af[s], bf[f], acc[s][f]);
    }

    float bcol[4];
    #pragma unroll
    for (int f = 0; f < 4; f++) bcol[f] = bias[n0 + wn*64 + f*16 + lr];

    #pragma unroll
    for (int s = 0; s < 4; s++) {
        const int mg = m0 + wm*64 + s*16 + lg*4;   // + r
        #pragma unroll
        for (int f = 0; f < 4; f++) {
            const int nc = n0 + wn*64 + f*16 + lr;
            if (MODE == 3) {
                float* o = (float*)outp;
                #pragma unroll
                for (int r = 0; r < 4; r++)
                    o[(size_t)(mg + r) * DM + nc] = acc[s][f][r] + bcol[f];
            } else {
                const int b = mg >> 11, seq = mg & 2047;
                const int head = nc >> 6, h = nc & 63;
                f16* o = (f16*)outp;
                if (MODE == 2) {
                    f16x4 pk = { (f16)(acc[s][f][0] + bcol[f]), (f16)(acc[s][f][1] + bcol[f]),
                                 (f16)(acc[s][f][2] + bcol[f]), (f16)(acc[s][f][3] + bcol[f]) };
                    *(f16x4*)&o[((size_t)((b*NH + head)*HD + h)) * S_ + seq] = pk;
                } else {
                    #pragma unroll
                    for (int r = 0; r < 4; r++)
                        o[((size_t)(b*NH + head) * S_ + seq + r) * HD + h] =
                            (f16)((acc[s][f][r] + bcol[f]) * scale);
                }
            }
        }
    }
}

// ---------------------------------------------------------------------------
// Softmax denominators: lpart[kc][b][q][n] = sum over this k-chunk of exp(S)
// grid (qt=128, kchunk=4, b=2), 256 thr; wave -> 4 heads. Plain stores (no atomics).
// ---------------------------------------------------------------------------
__global__ __launch_bounds__(256) void sums_k(const f16* __restrict__ qw,
    const f16* __restrict__ kw, const int* __restrict__ amask, float* __restrict__ lpart)
{
    const int tid = threadIdx.x, wave = tid >> 6, lane = tid & 63;
    const int lr = lane & 15, lg = lane >> 4;
    const int qt = blockIdx.x, kc = blockIdx.y, b = blockIdx.z;
    const int q0 = qt * 16, k0b = kc * 512;

    float rs[4][4];
    #pragma unroll
    for (int i = 0; i < 4; i++)
        #pragma unroll
        for (int r = 0; r < 4; r++) rs[i][r] = 0.f;

    f16x8 qf[4][2];
    #pragma unroll
    for (int hh = 0; hh < 4; hh++) {
        const int n = wave * 4 + hh;
        const f16* qp = qw + ((size_t)((b*NH + n) * S_) + q0 + lr) * HD + lg * 8;
        qf[hh][0] = *(const f16x8*)qp;
        qf[hh][1] = *(const f16x8*)(qp + 32);
    }
    for (int kt = 0; kt < 8; kt++) {
        const int k0 = k0b + kt * 64;
        int km[4];
        #pragma unroll
        for (int ct = 0; ct < 4; ct++) km[ct] = amask[b * S_ + k0 + ct*16 + lr];
        #pragma unroll
        for (int hh = 0; hh < 4; hh++) {
            const int n = wave * 4 + hh;
            const f16* kp = kw + ((size_t)((b*NH + n) * S_) + k0) * HD;
            #pragma unroll
            for (int ct = 0; ct < 4; ct++) {
                f16x8 b0 = *(const f16x8*)(kp + (size_t)(ct*16 + lr) * HD + lg*8);
                f16x8 b1 = *(const f16x8*)(kp + (size_t)(ct*16 + lr) * HD + 32 + lg*8);
                f32x4 sv = (f32x4)(0.f);
                sv = MFMA16(qf[hh][0], b0, sv);
                sv = MFMA16(qf[hh][1], b1, sv);
                #pragma unroll
                for (int r = 0; r < 4; r++) rs[hh][r] += km[ct] ? 0.f : __expf(sv[r]);
            }
        }
    }
    #pragma unroll
    for (int hh = 0; hh < 4; hh++) {
        #pragma unroll
        for (int r = 0; r < 4; r++) {
            float v = rs[hh][r];
            v += __shfl_xor(v, 1);  v += __shfl_xor(v, 2);
            v += __shfl_xor(v, 4);  v += __shfl_xor(v, 8);
            if (lr == 0)
                lpart[(size_t)kc * BSN +
                      (size_t)(b*S_ + q0 + lg*4 + r) * NH + wave*4 + hh] = v;
        }
    }
}

// ---------------------------------------------------------------------------
// Attention: recompute S, P = exp(S)/l (mask->0).  Per k-tile of 64:
//   1) each wave (2 heads x 16 q) computes P -> LDS [n][q][k+4pad] fp32,
//      runs PV from its own LDS data (no barrier needed),
//   2) barrier, cooperative write-pass: each thread packs 16 heads of one
//      (q,k) into 4x float4 -> fully coalesced 64B stores, barrier.
// grid (qt=128, kq=2, b=2), 512 thr. Dynamic LDS 16*16*68*4 = 69632 B.
// ---------------------------------------------------------------------------
__global__ __launch_bounds__(512) void attn_k(const f16* __restrict__ qw,
    const f16* __restrict__ kw, const f16* __restrict__ vt,
    const int* __restrict__ amask, const float* __restrict__ lpart,
    float* __restrict__ attn, float* __restrict__ op)
{
    extern __shared__ float Ps[];   // [16 n][16 q][68 k]
    const int tid = threadIdx.x, wave = tid >> 6, lane = tid & 63;
    const int lr = lane & 15, lg = lane >> 4;
    const int qt = blockIdx.x, kq = blockIdx.y, b = blockIdx.z;
    const int q0 = qt * 16;
    const int k0b = kq * 1024;

    f16x8 qf[2][2];
    float rl[2][4];
    #pragma unroll
    for (int hh = 0; hh < 2; hh++) {
        const int n = wave * 2 + hh;
        const f16* qp = qw + ((size_t)((b*NH + n) * S_) + q0 + lr) * HD + lg * 8;
        qf[hh][0] = *(const f16x8*)qp;
        qf[hh][1] = *(const f16x8*)(qp + 32);
        #pragma unroll
        for (int r = 0; r < 4; r++) {
            const float* lp = lpart + (size_t)(b*S_ + q0 + lg*4 + r) * NH + n;
            rl[hh][r] = 1.0f / (lp[0] + lp[BSN] + lp[2*BSN] + lp[3*BSN]);
        }
    }
    f32x4 accO[2][4];
    #pragma unroll
    for (int i = 0; i < 2; i++)
        #pragma unroll
        for (int j = 0; j < 4; j++) accO[i][j] = (f32x4)(0.f);

    for (int kt = 0; kt < 16; kt++) {
        const int k0 = k0b + kt * 64;
        int km[4];
        #pragma unroll
        for (int ct = 0; ct < 4; ct++) km[ct] = amask[b * S_ + k0 + ct*16 + lr];
        #pragma unroll
        for (int hh = 0; hh < 2; hh++) {
            const int n = wave * 2 + hh;
            const f16* kp = kw + ((size_t)((b*NH + n) * S_) + k0) * HD;
            f32x4 sfr[4];
            #pragma unroll
            for (int ct = 0; ct < 4; ct++) {
                f16x8 b0 = *(const f16x8*)(kp + (size_t)(ct*16 + lr) * HD + lg*8);
                f16x8 b1 = *(const f16x8*)(kp + (size_t)(ct*16 + lr) * HD + 32 + lg*8);
                f32x4 sv = (f32x4)(0.f);
                sv = MFMA16(qf[hh][0], b0, sv);
                sv = MFMA16(qf[hh][1], b1, sv);
                sfr[ct] = sv;
            }
            float* myP = Ps + (size_t)n * (16 * 68);
            #pragma unroll
            for (int ct = 0; ct < 4; ct++) {
                #pragma unroll
                for (int r = 0; r < 4; r++) {
                    float p = km[ct] ? 0.0f : __expf(sfr[ct][r]) * rl[hh][r];
                    myP[(lg*4 + r) * 68 + ct*16 + lr] = p;
                }
            }
            // PV A-fragments from own LDS tile (wave-local; compiler inserts lgkmcnt)
            f32x4 pa00 = *(const f32x4*)&myP[lr * 68 + lg*8];
            f32x4 pa01 = *(const f32x4*)&myP[lr * 68 + lg*8 + 4];
            f32x4 pa10 = *(const f32x4*)&myP[lr * 68 + 32 + lg*8];
            f32x4 pa11 = *(const f32x4*)&myP[lr * 68 + 32 + lg*8 + 4];
            f16x8 a0 = { (f16)pa00[0], (f16)pa00[1], (f16)pa00[2], (f16)pa00[3],
                         (f16)pa01[0], (f16)pa01[1], (f16)pa01[2], (f16)pa01[3] };
            f16x8 a1 = { (f16)pa10[0], (f16)pa10[1], (f16)pa10[2], (f16)pa10[3],
                         (f16)pa11[0], (f16)pa11[1], (f16)pa11[2], (f16)pa11[3] };
            #pragma unroll
            for (int hb = 0; hb < 4; hb++) {
                const f16* vp = vt + ((size_t)((b*NH + n) * HD) + hb*16 + lr) * S_ + k0;
                f16x8 v0 = *(const f16x8*)(vp + lg*8);
                f16x8 v1 = *(const f16x8*)(vp + 32 + lg*8);
                accO[hh][hb] = MFMA16(a0, v0, accO[hh][hb]);
                accO[hh][hb] = MFMA16(a1, v1, accO[hh][hb]);
            }
        }
        __syncthreads();
        // coalesced write-pass: thread -> (q, k) pair, packs all 16 heads
        {
            const int kk = tid & 63;
            #pragma unroll
            for (int it = 0; it < 2; it++) {
                const int q = (tid >> 6) + it * 8;
                float pv[16];
                #pragma unroll
                for (int n = 0; n < 16; n++)
                    pv[n] = Ps[n * (16*68) + q * 68 + kk];
                float* dst = attn + ((size_t)(b*S_ + q0 + q) * S_ + k0 + kk) * NH;
                #pragma unroll
                for (int j = 0; j < 4; j++)
                    *(float4*)(dst + j*4) = make_float4(pv[j*4+0], pv[j*4+1],
                                                        pv[j*4+2], pv[j*4+3]);
            }
        }
        __syncthreads();
    }
    float* opk = op + (size_t)kq * 4194304;
    #pragma unroll
    for (int hh = 0; hh < 2; hh++) {
        const int n = wave * 2 + hh;
        #pragma unroll
        for (int hb = 0; hb < 4; hb++)
            #pragma unroll
            for (int r = 0; r < 4; r++)
                opk[(size_t)(b*S_ + q0 + lg*4 + r) * DM + n*HD + hb*16 + lr] = accO[hh][hb][r];
    }
}

// ---------------------------------------------------------------------------
extern "C" void kernel_launch(void* const* d_in, const int* in_sizes, int n_in,
                              void* d_out, int out_size, void* d_ws, size_t ws_size,
                              hipStream_t stream)
{
    const float* query = (const float*)d_in[0];
    const float* key   = (const float*)d_in[1];
    const float* value = (const float*)d_in[2];
    const int*   amask = (const int*)d_in[3];
    const float* Wq = (const float*)d_in[4];
    const float* bq = (const float*)d_in[5];
    const float* Wk = (const float*)d_in[6];
    const float* bk = (const float*)d_in[7];
    const float* Wv = (const float*)d_in[8];
    const float* bv = (const float*)d_in[9];
    const float* Wo = (const float*)d_in[10];
    const float* bo = (const float*)d_in[11];

    char* ws = (char*)d_ws;
    f16*   qw = (f16*)(ws + 0);            //  8 MB
    f16*   kw = (f16*)(ws + 8388608);      //  8 MB
    f16*   vt = (f16*)(ws + 16777216);     //  8 MB
    float* lp = (float*)(ws + 25165824);   //  1 MB (4 partial-sum slabs)
    float* op = (float*)(ws + 26214400);   // 32 MB (2 k-half partials)

    float* out0 = (float*)d_out;
    float* attn = out0 + 4194304;

    dim3 blk(256);
    dim3 g1(32, 8);
    gemm_k<0><<<g1, blk, 0, stream>>>(query, Wq, bq, (void*)qw, SCAL);
    gemm_k<1><<<g1, blk, 0, stream>>>(key,   Wk, bk, (void*)kw, 1.0f);
    gemm_k<2><<<g1, blk, 0, stream>>>(value, Wv, bv, (void*)vt, 1.0f);
    sums_k<<<dim3(128, 4, 2), blk, 0, stream>>>(qw, kw, amask, lp);
    attn_k<<<dim3(128, 2, 2), dim3(512), 69632, stream>>>(qw, kw, vt, amask, lp, attn, op);
    gemm_k<3><<<g1, blk, 0, stream>>>(op, Wo, bo, d_out, 1.0f);
}